// Round 3
// baseline (1028.091 us; speedup 1.0000x reference)
//
#include <hip/hip_runtime.h>
#include <hip/hip_bf16.h>
#include <math.h>

#define NB 4
#define NN 4096
#define UU 512

using short8  = __attribute__((ext_vector_type(8))) short;
using bf16x8  = __attribute__((ext_vector_type(8))) __bf16;
using floatx4 = __attribute__((ext_vector_type(4))) float;

__device__ __forceinline__ floatx4 mfma16(short8 a, short8 b, floatx4 c) {
    return __builtin_amdgcn_mfma_f32_16x16x32_bf16(
        __builtin_bit_cast(bf16x8, a), __builtin_bit_cast(bf16x8, b), c, 0, 0, 0);
}

__device__ __forceinline__ unsigned short f2bf(float f) {
    union { float f; unsigned u; } v; v.f = f;
    return (unsigned short)((v.u + 0x7fffu + ((v.u >> 16) & 1u)) >> 16);
}
__device__ __forceinline__ float bf2f(unsigned short s) {
    union { unsigned u; float f; } v; v.u = ((unsigned)s) << 16; return v.f;
}

#define GLL16(gp, lp) __builtin_amdgcn_global_load_lds( \
    (const __attribute__((address_space(1))) void*)(gp), \
    (__attribute__((address_space(3))) void*)(lp), 16, 0, 0)

// ---------------------------------------------------------------- converts
__global__ void __launch_bounds__(256) k_cvt_x(const float* __restrict__ x,
                                               unsigned short* __restrict__ xb) {
    int i = (blockIdx.x * 256 + threadIdx.x) * 4;
    float4 v = *(const float4*)(x + i);
    ushort4 o;
    o.x = f2bf(v.x); o.y = f2bf(v.y); o.z = f2bf(v.z); o.w = f2bf(v.w);
    *(ushort4*)(xb + i) = o;
}

// all 4 weights in one launch: WT[z][n*512+k] = bf16(W[z][k*512+n])
__global__ void __launch_bounds__(256) k_cvt_w4(
    const float* __restrict__ Wq, const float* __restrict__ Wk,
    const float* __restrict__ Wv, const float* __restrict__ Wp,
    unsigned short* __restrict__ WTbase) {
    const int z = blockIdx.y;
    const float* W = (z == 0) ? Wq : (z == 1) ? Wk : (z == 2) ? Wv : Wp;
    int idx = blockIdx.x * 256 + threadIdx.x;  // 0..262143
    int n = idx >> 9, k = idx & 511;
    WTbase[(size_t)z * 262144 + idx] = f2bf(W[k * 512 + n]);
}

// ---------------------------------------------------------------- QKV proj
// z=0: Q row-major [b*N][U]
// z=1: K8 layout [b][d>>3][key][d&7]
// z=2: V8 layout [b][key>>3][d][key&7]
__global__ void __launch_bounds__(256, 2) k_proj(
    const unsigned short* __restrict__ Xb,
    const unsigned short* __restrict__ WqT, const unsigned short* __restrict__ WkT,
    const unsigned short* __restrict__ WvT,
    const float* __restrict__ bq, const float* __restrict__ bk, const float* __restrict__ bv,
    unsigned short* __restrict__ Q, unsigned short* __restrict__ K8,
    unsigned short* __restrict__ V8)
{
    __shared__ __align__(16) unsigned short As[128 * 32];
    __shared__ __align__(16) unsigned short Bs[128 * 32];
    const int z = blockIdx.z;
    const unsigned short* WT = (z == 0) ? WqT : (z == 1) ? WkT : WvT;
    const float* bias = (z == 0) ? bq : (z == 1) ? bk : bv;
    const int t = threadIdx.x, wave = t >> 6, lane = t & 63;
    const int quad = lane >> 4, l16 = lane & 15;
    const int m0 = blockIdx.x * 128, n0 = blockIdx.y * 128;
    const int wm = wave >> 1, wn = wave & 1;

    const int srow = wave * 32 + (lane >> 2);
    const int scol = (lane & 3) * 8;
    const unsigned short* gA = Xb + (size_t)(m0 + srow) * UU + scol;
    const unsigned short* gB = WT + (size_t)(n0 + srow) * UU + scol;
    unsigned short* lA = As + wave * 1024;
    unsigned short* lB = Bs + wave * 1024;

    floatx4 acc[4][4] = {};

    for (int k0 = 0; k0 < UU; k0 += 32) {
        GLL16(gA + k0, lA);
        GLL16(gA + k0 + 16 * UU, lA + 512);
        GLL16(gB + k0, lB);
        GLL16(gB + k0 + 16 * UU, lB + 512);
        __syncthreads();
        short8 a[4], b[4];
        #pragma unroll
        for (int i = 0; i < 4; i++)
            a[i] = *(const short8*)(As + (wm * 64 + i * 16 + l16) * 32 + quad * 8);
        #pragma unroll
        for (int j = 0; j < 4; j++)
            b[j] = *(const short8*)(Bs + (wn * 64 + j * 16 + l16) * 32 + quad * 8);
        #pragma unroll
        for (int i = 0; i < 4; i++)
            #pragma unroll
            for (int j = 0; j < 4; j++)
                acc[i][j] = mfma16(a[i], b[j], acc[i][j]);
        __syncthreads();
    }

    #pragma unroll
    for (int j = 0; j < 4; j++) {
        const int n = n0 + wn * 64 + j * 16 + l16;
        const float bv_ = bias[n];
        #pragma unroll
        for (int i = 0; i < 4; i++) {
            const int mb = m0 + wm * 64 + i * 16 + quad * 4;
            const int bb = mb >> 12, tok = mb & (NN - 1);
            if (z == 0) {
                #pragma unroll
                for (int r = 0; r < 4; r++)
                    Q[(size_t)(mb + r) * UU + n] = f2bf(acc[i][j][r] + bv_);
            } else if (z == 1) {
                const size_t base = (size_t)bb * NN * UU + (size_t)(n >> 3) * (NN * 8)
                                  + (size_t)tok * 8 + (n & 7);
                #pragma unroll
                for (int r = 0; r < 4; r++)
                    K8[base + (size_t)r * 8] = f2bf(acc[i][j][r] + bv_);
            } else {
                ushort4 o;
                o.x = f2bf(acc[i][j][0] + bv_);
                o.y = f2bf(acc[i][j][1] + bv_);
                o.z = f2bf(acc[i][j][2] + bv_);
                o.w = f2bf(acc[i][j][3] + bv_);
                *(ushort4*)(V8 + (size_t)bb * NN * UU + (size_t)(tok >> 3) * (UU * 8)
                            + (size_t)n * 8 + (tok & 7)) = o;
            }
        }
    }
}

// ---------------------------------------------------------------- flash attention
// 8 waves, BM=64, BN=64. wave = (qg<<2) | (half<<1) | kh
//   S : wave computes 32 q-rows (qg) x 32 keys (kh) over 256 dims (half),
//       partials merged with ds_add_f32 into S_f (zeroed during prior PV).
//   PV: wave computes 32 q-rows (qg) x 256 dims (half) over 32 keys (kh),
//       key-half partial O merged once in epilogue via LDS.
__global__ void __launch_bounds__(512, 2) k_flash(
    const unsigned short* __restrict__ Q,
    const unsigned short* __restrict__ K8,
    const unsigned short* __restrict__ V8,
    unsigned short* __restrict__ ctx)
{
    __shared__ __align__(16) char smem[158464];
    unsigned short* Ks = (unsigned short*)smem;             // 64 KB [dc 64][key 64][kk 8]
    unsigned short* Vs = (unsigned short*)(smem + 65536);   // 64 KB [kc 8][d 512][kk 8]
    float*          S_f = (float*)(smem + 131072);          // 64 x 68 fp32
    unsigned short* P_l = (unsigned short*)(smem + 148480); // 64 x 72 bf16
    float*          m_l = (float*)(smem + 157696);
    float*          l_l = m_l + 64;
    float*          a_l = m_l + 128;

    const int b = blockIdx.y;
    const int q0 = blockIdx.x * 64;
    const int t = threadIdx.x;
    const int wave = t >> 6, lane = t & 63, quad = lane >> 4, l16 = lane & 15;
    const int qg = wave >> 2;          // q-group (32 rows)
    const int half = (wave >> 1) & 1;  // dim-half (S) / d-half (PV)
    const int kh = wave & 1;           // key-half (32 keys)

    if (t < 64) { m_l[t] = -INFINITY; l_l[t] = 0.f; }
    // zero S for first iteration
    { const int row = t >> 3, c = (t & 7) * 8;
      *(float4*)(S_f + row * 68 + c) = float4{0,0,0,0};
      *(float4*)(S_f + row * 68 + c + 4) = float4{0,0,0,0}; }

    // Q frags: 32 rows (2 q-tiles) x 256 dims (half) -> 16 short8 = 64 VGPR
    const unsigned short* qp = Q + (size_t)(b * NN + q0 + qg * 32 + l16) * UU
                             + half * 256 + quad * 8;
    short8 qf[16];
    #pragma unroll
    for (int qt = 0; qt < 2; qt++)
        #pragma unroll
        for (int kk = 0; kk < 8; kk++)
            qf[qt * 8 + kk] = *(const short8*)(qp + qt * 16 * UU + kk * 32);

    const unsigned short* K8b = K8 + (size_t)b * NN * UU;
    const unsigned short* V8b = V8 + (size_t)b * NN * UU;

    // prologue: stage K(0)
    #pragma unroll
    for (int j = 0; j < 8; j++) {
        const int dc = wave * 8 + j;
        GLL16(K8b + (size_t)dc * (NN * 8) + lane * 8, Ks + dc * 512 + lane * 8);
    }

    floatx4 o[2][16] = {};
    const float sscale = 0.04419417382415922f * 1.4426950408889634f;  // 1/sqrt(512)*log2(e)

    __syncthreads();  // K(0) staged, m/l/S init visible

    for (int kt = 0; kt < NN; kt += 64) {
        // stage V(kt) (prev PV reads done at loop-end barrier; drains at barrier1)
        #pragma unroll
        for (int j = 0; j < 8; j++) {
            const int c = wave * 8 + j;
            GLL16(V8b + (size_t)kt * 512 + (size_t)c * 512 + lane * 8, Vs + c * 512 + lane * 8);
        }

        // ---- S partial: 32q x 32k over this wave's 256 dims
        floatx4 sacc[2][2] = {};
        #pragma unroll
        for (int kk = 0; kk < 8; kk++) {
            #pragma unroll
            for (int k2 = 0; k2 < 2; k2++) {
                const int dc = half * 32 + kk * 4 + quad;
                const int key = kh * 32 + k2 * 16 + l16;
                short8 bfrag = *(const short8*)(Ks + dc * 512 + key * 8);
                sacc[0][k2] = mfma16(qf[kk],     bfrag, sacc[0][k2]);
                sacc[1][k2] = mfma16(qf[8 + kk], bfrag, sacc[1][k2]);
            }
        }
        #pragma unroll
        for (int qt = 0; qt < 2; qt++)
            #pragma unroll
            for (int k2 = 0; k2 < 2; k2++) {
                const int row = qg * 32 + qt * 16 + quad * 4;
                const int col = kh * 32 + k2 * 16 + l16;
                #pragma unroll
                for (int i = 0; i < 4; i++)
                    atomicAdd(&S_f[(row + i) * 68 + col], sacc[qt][k2][i] * sscale);
            }
        __syncthreads();   // barrier1: S complete; V(kt) drained

        // ---- online softmax stats (8 threads per row, 8 cols each)
        {
            const int row = t >> 3, c8 = (t & 7) * 8;
            const float4* sp = (const float4*)(S_f + row * 68 + c8);
            float4 va = sp[0], vb = sp[1];
            float mx = fmaxf(fmaxf(fmaxf(va.x, va.y), fmaxf(va.z, va.w)),
                             fmaxf(fmaxf(vb.x, vb.y), fmaxf(vb.z, vb.w)));
            mx = fmaxf(mx, __shfl_xor(mx, 1, 8));
            mx = fmaxf(mx, __shfl_xor(mx, 2, 8));
            mx = fmaxf(mx, __shfl_xor(mx, 4, 8));
            const float m_old = m_l[row];
            const float m_new = fmaxf(m_old, mx);
            float p[8] = { exp2f(va.x - m_new), exp2f(va.y - m_new),
                           exp2f(va.z - m_new), exp2f(va.w - m_new),
                           exp2f(vb.x - m_new), exp2f(vb.y - m_new),
                           exp2f(vb.z - m_new), exp2f(vb.w - m_new) };
            short8 pv; float sum = 0.f;
            #pragma unroll
            for (int j = 0; j < 8; j++) {
                unsigned short us = f2bf(p[j]);
                pv[j] = (short)us;
                sum += bf2f(us);
            }
            *(short8*)(P_l + row * 72 + c8) = pv;
            sum += __shfl_xor(sum, 1, 8);
            sum += __shfl_xor(sum, 2, 8);
            sum += __shfl_xor(sum, 4, 8);
            if ((t & 7) == 0) {
                const float alpha = exp2f(m_old - m_new);
                a_l[row] = alpha;
                m_l[row] = m_new;
                l_l[row] = l_l[row] * alpha + sum;
            }
        }
        __syncthreads();   // barrier2: P/stats visible; S reads done

        // zero S for next iteration (next adds happen after barrier3)
        { const int row = t >> 3, c = (t & 7) * 8;
          *(float4*)(S_f + row * 68 + c) = float4{0,0,0,0};
          *(float4*)(S_f + row * 68 + c + 4) = float4{0,0,0,0}; }

        // stage K(kt+64) — drains at barrier3, hidden behind PV
        if (kt + 64 < NN) {
            #pragma unroll
            for (int j = 0; j < 8; j++) {
                const int dc = wave * 8 + j;
                GLL16(K8b + (size_t)dc * (NN * 8) + (size_t)(kt + 64 + lane) * 8,
                      Ks + dc * 512 + lane * 8);
            }
        }

        // ---- PV partial: O[32q x 256d] += P[32q x 32k(kh)] @ V[32k x 256d]
        float al[8];
        #pragma unroll
        for (int qt = 0; qt < 2; qt++)
            #pragma unroll
            for (int i = 0; i < 4; i++)
                al[qt * 4 + i] = a_l[qg * 32 + qt * 16 + quad * 4 + i];
        #pragma unroll
        for (int qt = 0; qt < 2; qt++)
            #pragma unroll
            for (int dt = 0; dt < 16; dt++)
                #pragma unroll
                for (int i = 0; i < 4; i++)
                    o[qt][dt][i] *= al[qt * 4 + i];

        short8 pa[2];
        #pragma unroll
        for (int qt = 0; qt < 2; qt++)
            pa[qt] = *(const short8*)(P_l + (qg * 32 + qt * 16 + l16) * 72 + kh * 32 + quad * 8);
        #pragma unroll
        for (int dt = 0; dt < 16; dt++) {
            const int d = half * 256 + dt * 16 + l16;
            short8 vb = *(const short8*)(Vs + (kh * 4 + quad) * 4096 + d * 8);
            o[0][dt] = mfma16(pa[0], vb, o[0][dt]);
            o[1][dt] = mfma16(pa[1], vb, o[1][dt]);
        }
        __syncthreads();   // barrier3: PV reads done; K(kt+64) drained; S zeroed
    }

    // ---- epilogue: merge key-half partials via LDS, normalize, store
    float* Obuf = (float*)smem;  // 64 x 512 fp32 = 128 KB (over Ks+Vs)
    if (kh == 0) {
        #pragma unroll
        for (int qt = 0; qt < 2; qt++)
            #pragma unroll
            for (int dt = 0; dt < 16; dt++) {
                const int d = half * 256 + dt * 16 + l16;
                #pragma unroll
                for (int i = 0; i < 4; i++)
                    Obuf[(qg * 32 + qt * 16 + quad * 4 + i) * 512 + d] = o[qt][dt][i];
            }
    }
    __syncthreads();
    if (kh == 1) {
        float linv[8];
        #pragma unroll
        for (int qt = 0; qt < 2; qt++)
            #pragma unroll
            for (int i = 0; i < 4; i++)
                linv[qt * 4 + i] = 1.f / l_l[qg * 32 + qt * 16 + quad * 4 + i];
        #pragma unroll
        for (int qt = 0; qt < 2; qt++)
            #pragma unroll
            for (int dt = 0; dt < 16; dt++) {
                const int d = half * 256 + dt * 16 + l16;
                #pragma unroll
                for (int i = 0; i < 4; i++) {
                    const int row = qg * 32 + qt * 16 + quad * 4 + i;
                    const float val = (o[qt][dt][i] + Obuf[row * 512 + d]) * linv[qt * 4 + i];
                    ctx[(size_t)(b * NN + q0 + row) * UU + d] = f2bf(val);
                }
            }
    }
}

// ---------------------------------------------------------------- out proj + residual
__global__ void __launch_bounds__(256, 2) k_out(
    const unsigned short* __restrict__ Cx,
    const unsigned short* __restrict__ WpT,
    const float* __restrict__ bp,
    const float* __restrict__ x,
    float* __restrict__ out)
{
    __shared__ __align__(16) unsigned short As[128 * 32];
    __shared__ __align__(16) unsigned short Bs[128 * 32];
    const int t = threadIdx.x, wave = t >> 6, lane = t & 63;
    const int quad = lane >> 4, l16 = lane & 15;
    const int m0 = blockIdx.x * 128, n0 = blockIdx.y * 128;
    const int wm = wave >> 1, wn = wave & 1;
    const int srow = wave * 32 + (lane >> 2);
    const int scol = (lane & 3) * 8;
    const unsigned short* gA = Cx + (size_t)(m0 + srow) * UU + scol;
    const unsigned short* gB = WpT + (size_t)(n0 + srow) * UU + scol;
    unsigned short* lA = As + wave * 1024;
    unsigned short* lB = Bs + wave * 1024;

    floatx4 acc[4][4] = {};

    for (int k0 = 0; k0 < UU; k0 += 32) {
        GLL16(gA + k0, lA);
        GLL16(gA + k0 + 16 * UU, lA + 512);
        GLL16(gB + k0, lB);
        GLL16(gB + k0 + 16 * UU, lB + 512);
        __syncthreads();
        short8 a[4], b[4];
        #pragma unroll
        for (int i = 0; i < 4; i++)
            a[i] = *(const short8*)(As + (wm * 64 + i * 16 + l16) * 32 + quad * 8);
        #pragma unroll
        for (int j = 0; j < 4; j++)
            b[j] = *(const short8*)(Bs + (wn * 64 + j * 16 + l16) * 32 + quad * 8);
        #pragma unroll
        for (int i = 0; i < 4; i++)
            #pragma unroll
            for (int j = 0; j < 4; j++)
                acc[i][j] = mfma16(a[i], b[j], acc[i][j]);
        __syncthreads();
    }

    #pragma unroll
    for (int j = 0; j < 4; j++) {
        const int n = n0 + wn * 64 + j * 16 + l16;
        const float bv_ = bp[n];
        #pragma unroll
        for (int i = 0; i < 4; i++) {
            const int mb = m0 + wm * 64 + i * 16 + quad * 4;
            #pragma unroll
            for (int r = 0; r < 4; r++) {
                const size_t idx = (size_t)(mb + r) * UU + n;
                out[idx] = acc[i][j][r] + bv_ + x[idx];
            }
        }
    }
}

// ---------------------------------------------------------------- launch
extern "C" void kernel_launch(void* const* d_in, const int* in_sizes, int n_in,
                              void* d_out, int out_size, void* d_ws, size_t ws_size,
                              hipStream_t stream)
{
    const float* x  = (const float*)d_in[0];
    const float* Wq = (const float*)d_in[1];
    const float* bq = (const float*)d_in[2];
    const float* Wk = (const float*)d_in[3];
    const float* bk = (const float*)d_in[4];
    const float* Wv = (const float*)d_in[5];
    const float* bv = (const float*)d_in[6];
    const float* Wp = (const float*)d_in[7];
    const float* bp = (const float*)d_in[8];
    float* out = (float*)d_out;

    char* ws = (char*)d_ws;
    unsigned short* Xb  = (unsigned short*)(ws);              // 16 MB  bf16 x
    unsigned short* WTb = (unsigned short*)(ws + 16777216);   // 4 x 512 KB contiguous
    unsigned short* WqT = WTb;
    unsigned short* WkT = WTb + 262144;
    unsigned short* WvT = WTb + 524288;
    unsigned short* WpT = WTb + 786432;
    unsigned short* Qm  = (unsigned short*)(ws + 18874368);   // 16 MB [b*N][U]
    unsigned short* K8m = (unsigned short*)(ws + 35651584);   // 16 MB [b][d>>3][key][d&7]
    unsigned short* V8m = (unsigned short*)(ws + 52428800);   // 16 MB [b][key>>3][d][key&7]
    unsigned short* Cx  = (unsigned short*)(ws + 69206016);   // 16 MB [b*N][U]

    hipLaunchKernelGGL(k_cvt_x, dim3(8192), dim3(256), 0, stream, x, Xb);
    hipLaunchKernelGGL(k_cvt_w4, dim3(1024, 4), dim3(256), 0, stream, Wq, Wk, Wv, Wp, WTb);
    hipLaunchKernelGGL(k_proj, dim3(128, 4, 3), dim3(256), 0, stream,
                       Xb, WqT, WkT, WvT, bq, bk, bv, Qm, K8m, V8m);
    hipLaunchKernelGGL(k_flash, dim3(64, 4), dim3(512), 0, stream, Qm, K8m, V8m, Cx);
    hipLaunchKernelGGL(k_out, dim3(128, 4), dim3(256), 0, stream, Cx, WpT, bp, x, out);
}

// Round 4
// 399.333 us; speedup vs baseline: 2.5745x; 2.5745x over previous
//
#include <hip/hip_runtime.h>
#include <hip/hip_bf16.h>
#include <math.h>

#define NB 4
#define NN 4096
#define UU 512

using short8   = __attribute__((ext_vector_type(8))) short;
using bf16x8   = __attribute__((ext_vector_type(8))) __bf16;
using floatx4  = __attribute__((ext_vector_type(4))) float;
using floatx16 = __attribute__((ext_vector_type(16))) float;

__device__ __forceinline__ floatx4 mfma16(short8 a, short8 b, floatx4 c) {
    return __builtin_amdgcn_mfma_f32_16x16x32_bf16(
        __builtin_bit_cast(bf16x8, a), __builtin_bit_cast(bf16x8, b), c, 0, 0, 0);
}
__device__ __forceinline__ floatx16 mfma32(short8 a, short8 b, floatx16 c) {
    return __builtin_amdgcn_mfma_f32_32x32x16_bf16(
        __builtin_bit_cast(bf16x8, a), __builtin_bit_cast(bf16x8, b), c, 0, 0, 0);
}

__device__ __forceinline__ unsigned short f2bf(float f) {
    union { float f; unsigned u; } v; v.f = f;
    return (unsigned short)((v.u + 0x7fffu + ((v.u >> 16) & 1u)) >> 16);
}
__device__ __forceinline__ float bf2f(unsigned short s) {
    union { unsigned u; float f; } v; v.u = ((unsigned)s) << 16; return v.f;
}

#define GLL16(gp, lp) __builtin_amdgcn_global_load_lds( \
    (const __attribute__((address_space(1))) void*)(gp), \
    (__attribute__((address_space(3))) void*)(lp), 16, 0, 0)

// ---------------------------------------------------------------- converts
__global__ void __launch_bounds__(256) k_cvt_x(const float* __restrict__ x,
                                               unsigned short* __restrict__ xb) {
    int i = (blockIdx.x * 256 + threadIdx.x) * 4;
    float4 v = *(const float4*)(x + i);
    ushort4 o;
    o.x = f2bf(v.x); o.y = f2bf(v.y); o.z = f2bf(v.z); o.w = f2bf(v.w);
    *(ushort4*)(xb + i) = o;
}

__global__ void __launch_bounds__(256) k_cvt_w4(
    const float* __restrict__ Wq, const float* __restrict__ Wk,
    const float* __restrict__ Wv, const float* __restrict__ Wp,
    unsigned short* __restrict__ WTbase) {
    const int z = blockIdx.y;
    const float* W = (z == 0) ? Wq : (z == 1) ? Wk : (z == 2) ? Wv : Wp;
    int idx = blockIdx.x * 256 + threadIdx.x;
    int n = idx >> 9, k = idx & 511;
    WTbase[(size_t)z * 262144 + idx] = f2bf(W[k * 512 + n]);
}

// ---------------------------------------------------------------- QKV proj
// z=0: Q row-major [b*N][U]
// z=1: K8 layout [b][d>>3][key][d&7]
// z=2: V8 layout [b][key>>3][d][key&7]
__global__ void __launch_bounds__(256, 2) k_proj(
    const unsigned short* __restrict__ Xb,
    const unsigned short* __restrict__ WqT, const unsigned short* __restrict__ WkT,
    const unsigned short* __restrict__ WvT,
    const float* __restrict__ bq, const float* __restrict__ bk, const float* __restrict__ bv,
    unsigned short* __restrict__ Q, unsigned short* __restrict__ K8,
    unsigned short* __restrict__ V8)
{
    __shared__ __align__(16) unsigned short As[128 * 32];
    __shared__ __align__(16) unsigned short Bs[128 * 32];
    const int z = blockIdx.z;
    const unsigned short* WT = (z == 0) ? WqT : (z == 1) ? WkT : WvT;
    const float* bias = (z == 0) ? bq : (z == 1) ? bk : bv;
    const int t = threadIdx.x, wave = t >> 6, lane = t & 63;
    const int quad = lane >> 4, l16 = lane & 15;
    const int m0 = blockIdx.x * 128, n0 = blockIdx.y * 128;
    const int wm = wave >> 1, wn = wave & 1;

    const int srow = wave * 32 + (lane >> 2);
    const int scol = (lane & 3) * 8;
    const unsigned short* gA = Xb + (size_t)(m0 + srow) * UU + scol;
    const unsigned short* gB = WT + (size_t)(n0 + srow) * UU + scol;
    unsigned short* lA = As + wave * 1024;
    unsigned short* lB = Bs + wave * 1024;

    floatx4 acc[4][4] = {};

    for (int k0 = 0; k0 < UU; k0 += 32) {
        GLL16(gA + k0, lA);
        GLL16(gA + k0 + 16 * UU, lA + 512);
        GLL16(gB + k0, lB);
        GLL16(gB + k0 + 16 * UU, lB + 512);
        __syncthreads();
        short8 a[4], b[4];
        #pragma unroll
        for (int i = 0; i < 4; i++)
            a[i] = *(const short8*)(As + (wm * 64 + i * 16 + l16) * 32 + quad * 8);
        #pragma unroll
        for (int j = 0; j < 4; j++)
            b[j] = *(const short8*)(Bs + (wn * 64 + j * 16 + l16) * 32 + quad * 8);
        #pragma unroll
        for (int i = 0; i < 4; i++)
            #pragma unroll
            for (int j = 0; j < 4; j++)
                acc[i][j] = mfma16(a[i], b[j], acc[i][j]);
        __syncthreads();
    }

    #pragma unroll
    for (int j = 0; j < 4; j++) {
        const int n = n0 + wn * 64 + j * 16 + l16;
        const float bv_ = bias[n];
        #pragma unroll
        for (int i = 0; i < 4; i++) {
            const int mb = m0 + wm * 64 + i * 16 + quad * 4;
            const int bb = mb >> 12, tok = mb & (NN - 1);
            if (z == 0) {
                #pragma unroll
                for (int r = 0; r < 4; r++)
                    Q[(size_t)(mb + r) * UU + n] = f2bf(acc[i][j][r] + bv_);
            } else if (z == 1) {
                const size_t base = (size_t)bb * NN * UU + (size_t)(n >> 3) * (NN * 8)
                                  + (size_t)tok * 8 + (n & 7);
                #pragma unroll
                for (int r = 0; r < 4; r++)
                    K8[base + (size_t)r * 8] = f2bf(acc[i][j][r] + bv_);
            } else {
                ushort4 o;
                o.x = f2bf(acc[i][j][0] + bv_);
                o.y = f2bf(acc[i][j][1] + bv_);
                o.z = f2bf(acc[i][j][2] + bv_);
                o.w = f2bf(acc[i][j][3] + bv_);
                *(ushort4*)(V8 + (size_t)bb * NN * UU + (size_t)(tok >> 3) * (UU * 8)
                            + (size_t)n * 8 + (tok & 7)) = o;
            }
        }
    }
}

// ---------------------------------------------------------------- flash attention
// 8 waves = (rg 0..1, cg 0..1, dh 0..1). BM=64 q-rows/block, BN=64 keys/iter.
// 32x32x16 MFMAs. S: wave computes tile (rg,cg) over dim-half dh; merge dh=1
// partials via plain RMW (NO atomics). PV: wave owns 32 q-rows x 128 dims over
// all 64 keys -> no epilogue merge.
__global__ void __launch_bounds__(512, 1) k_flash(
    const unsigned short* __restrict__ Q,
    const unsigned short* __restrict__ K8,
    const unsigned short* __restrict__ V8,
    unsigned short* __restrict__ ctx)
{
    __shared__ __align__(16) char smem[158464];
    unsigned short* Ks  = (unsigned short*)smem;             // 64 KB [dc64][key64][kk8]
    unsigned short* Vs  = (unsigned short*)(smem + 65536);   // 64 KB [kc8][d512][kk8]
    float*          S_f = (float*)(smem + 131072);           // 64 x 68 fp32
    unsigned short* P_l = (unsigned short*)(smem + 148480);  // 64 x 72 bf16
    float*          m_l = (float*)(smem + 157696);
    float*          l_l = m_l + 64;
    float*          a_l = m_l + 128;

    const int b = blockIdx.y, q0 = blockIdx.x * 64;
    const int t = threadIdx.x, wave = t >> 6, lane = t & 63;
    const int l31 = lane & 31, ah = lane >> 5;
    const int rg = wave >> 2, cg = (wave >> 1) & 1, dh = wave & 1;

    if (t < 64) { m_l[t] = -INFINITY; l_l[t] = 0.f; }

    // Q frags: rows rg*32+l31, dims dh*256 + ks*16 + ah*8 + j  (64 VGPR)
    const unsigned short* qp = Q + (size_t)(b * NN + q0 + rg * 32 + l31) * UU
                             + dh * 256 + ah * 8;
    short8 qf[16];
    #pragma unroll
    for (int ks = 0; ks < 16; ks++) qf[ks] = *(const short8*)(qp + ks * 16);

    const unsigned short* K8b = K8 + (size_t)b * NN * UU;
    const unsigned short* V8b = V8 + (size_t)b * NN * UU;

    // prologue: stage K(0)
    #pragma unroll
    for (int j = 0; j < 8; j++) {
        const int dc = wave * 8 + j;
        GLL16(K8b + (size_t)dc * (NN * 8) + lane * 8, Ks + dc * 512 + lane * 8);
    }

    floatx16 o[4] = {};   // 4 d-tiles of 32 dims, rows rg*32.. (64 VGPR)
    const float sscale = 0.04419417382415922f * 1.4426950408889634f;  // 1/sqrt(512)*log2e
    const int D0 = (cg * 2 + dh) * 128;

    __syncthreads();  // K(0) staged, m/l init visible

    for (int kt = 0; kt < NN; kt += 64) {
        // stage V(kt): drains at b1, hidden behind S
        #pragma unroll
        for (int j = 0; j < 8; j++) {
            const int c = wave * 8 + j;
            GLL16(V8b + (size_t)kt * 512 + (size_t)c * 512 + lane * 8, Vs + c * 512 + lane * 8);
        }

        // ---- S partial: tile (rg,cg), dims dh*256..+255
        floatx16 sacc = {};
        #pragma unroll
        for (int ks = 0; ks < 16; ks++) {
            short8 bfrag = *(const short8*)(Ks + (dh * 32 + ks * 2 + ah) * 512
                                            + (cg * 32 + l31) * 8);
            sacc = mfma32(qf[ks], bfrag, sacc);
        }
        if (dh == 0) {
            #pragma unroll
            for (int r = 0; r < 16; r++) {
                const int row = rg * 32 + (r & 3) + 8 * (r >> 2) + 4 * ah;
                S_f[row * 68 + cg * 32 + l31] = sacc[r] * sscale;
            }
        }
        __syncthreads();   // b1: dh0 S visible; V drained; Ks reads done
        if (dh == 1) {
            #pragma unroll
            for (int r = 0; r < 16; r++) {
                const int row = rg * 32 + (r & 3) + 8 * (r >> 2) + 4 * ah;
                S_f[row * 68 + cg * 32 + l31] += sacc[r] * sscale;
            }
        }
        __syncthreads();   // b2: S complete

        // ---- online softmax stats (8 threads per row, 8 cols each)
        {
            const int row = t >> 3, c8 = (t & 7) * 8;
            const float4* sp = (const float4*)(S_f + row * 68 + c8);
            float4 va = sp[0], vb = sp[1];
            float mx = fmaxf(fmaxf(fmaxf(va.x, va.y), fmaxf(va.z, va.w)),
                             fmaxf(fmaxf(vb.x, vb.y), fmaxf(vb.z, vb.w)));
            mx = fmaxf(mx, __shfl_xor(mx, 1, 8));
            mx = fmaxf(mx, __shfl_xor(mx, 2, 8));
            mx = fmaxf(mx, __shfl_xor(mx, 4, 8));
            const float m_old = m_l[row];
            const float m_new = fmaxf(m_old, mx);
            float p[8] = { exp2f(va.x - m_new), exp2f(va.y - m_new),
                           exp2f(va.z - m_new), exp2f(va.w - m_new),
                           exp2f(vb.x - m_new), exp2f(vb.y - m_new),
                           exp2f(vb.z - m_new), exp2f(vb.w - m_new) };
            short8 pv; float sum = 0.f;
            #pragma unroll
            for (int j = 0; j < 8; j++) {
                unsigned short us = f2bf(p[j]);
                pv[j] = (short)us;
                sum += bf2f(us);
            }
            *(short8*)(P_l + row * 72 + c8) = pv;
            sum += __shfl_xor(sum, 1, 8);
            sum += __shfl_xor(sum, 2, 8);
            sum += __shfl_xor(sum, 4, 8);
            if ((t & 7) == 0) {
                const float alpha = exp2f(m_old - m_new);
                a_l[row] = alpha;
                m_l[row] = m_new;
                l_l[row] = l_l[row] * alpha + sum;
            }
        }
        __syncthreads();   // b3: P/stats visible; S reads done

        // stage K(kt+64): drains at b4, hidden behind PV
        if (kt + 64 < NN) {
            #pragma unroll
            for (int j = 0; j < 8; j++) {
                const int dc = wave * 8 + j;
                GLL16(K8b + (size_t)dc * (NN * 8) + (size_t)(kt + 64 + lane) * 8,
                      Ks + dc * 512 + lane * 8);
            }
        }

        // ---- PV: O[rg*32+32 rows][D0..D0+127] += P @ V  (all 64 keys)
        float alv[16];
        #pragma unroll
        for (int g = 0; g < 4; g++) {
            float4 v = *(const float4*)(a_l + rg * 32 + 4 * ah + 8 * g);
            alv[g * 4 + 0] = v.x; alv[g * 4 + 1] = v.y;
            alv[g * 4 + 2] = v.z; alv[g * 4 + 3] = v.w;
        }
        #pragma unroll
        for (int dt = 0; dt < 4; dt++)
            #pragma unroll
            for (int r = 0; r < 16; r++)
                o[dt][r] *= alv[r];

        short8 pa[4];
        #pragma unroll
        for (int ks = 0; ks < 4; ks++)
            pa[ks] = *(const short8*)(P_l + (rg * 32 + l31) * 72 + ks * 16 + ah * 8);
        #pragma unroll
        for (int dt = 0; dt < 4; dt++) {
            #pragma unroll
            for (int ks = 0; ks < 4; ks++) {
                short8 vb = *(const short8*)(Vs + (size_t)(ks * 2 + ah) * 4096
                                             + (D0 + dt * 32 + l31) * 8);
                o[dt] = mfma32(pa[ks], vb, o[dt]);
            }
        }
        __syncthreads();   // b4: P_l/Vs reads done; K(kt+64) drained
    }

    // ---- epilogue: normalize, store (each wave owns disjoint rows x dims)
    float lnv[16];
    #pragma unroll
    for (int g = 0; g < 4; g++) {
        float4 v = *(const float4*)(l_l + rg * 32 + 4 * ah + 8 * g);
        lnv[g * 4 + 0] = 1.f / v.x; lnv[g * 4 + 1] = 1.f / v.y;
        lnv[g * 4 + 2] = 1.f / v.z; lnv[g * 4 + 3] = 1.f / v.w;
    }
    #pragma unroll
    for (int dt = 0; dt < 4; dt++) {
        #pragma unroll
        for (int r = 0; r < 16; r++) {
            const int row = q0 + rg * 32 + (r & 3) + 8 * (r >> 2) + 4 * ah;
            const int d = D0 + dt * 32 + l31;
            ctx[(size_t)(b * NN + row) * UU + d] = f2bf(o[dt][r] * lnv[r]);
        }
    }
}

// ---------------------------------------------------------------- out proj + residual
__global__ void __launch_bounds__(256, 2) k_out(
    const unsigned short* __restrict__ Cx,
    const unsigned short* __restrict__ WpT,
    const float* __restrict__ bp,
    const float* __restrict__ x,
    float* __restrict__ out)
{
    __shared__ __align__(16) unsigned short As[128 * 32];
    __shared__ __align__(16) unsigned short Bs[128 * 32];
    const int t = threadIdx.x, wave = t >> 6, lane = t & 63;
    const int quad = lane >> 4, l16 = lane & 15;
    const int m0 = blockIdx.x * 128, n0 = blockIdx.y * 128;
    const int wm = wave >> 1, wn = wave & 1;
    const int srow = wave * 32 + (lane >> 2);
    const int scol = (lane & 3) * 8;
    const unsigned short* gA = Cx + (size_t)(m0 + srow) * UU + scol;
    const unsigned short* gB = WpT + (size_t)(n0 + srow) * UU + scol;
    unsigned short* lA = As + wave * 1024;
    unsigned short* lB = Bs + wave * 1024;

    floatx4 acc[4][4] = {};

    for (int k0 = 0; k0 < UU; k0 += 32) {
        GLL16(gA + k0, lA);
        GLL16(gA + k0 + 16 * UU, lA + 512);
        GLL16(gB + k0, lB);
        GLL16(gB + k0 + 16 * UU, lB + 512);
        __syncthreads();
        short8 a[4], b[4];
        #pragma unroll
        for (int i = 0; i < 4; i++)
            a[i] = *(const short8*)(As + (wm * 64 + i * 16 + l16) * 32 + quad * 8);
        #pragma unroll
        for (int j = 0; j < 4; j++)
            b[j] = *(const short8*)(Bs + (wn * 64 + j * 16 + l16) * 32 + quad * 8);
        #pragma unroll
        for (int i = 0; i < 4; i++)
            #pragma unroll
            for (int j = 0; j < 4; j++)
                acc[i][j] = mfma16(a[i], b[j], acc[i][j]);
        __syncthreads();
    }

    #pragma unroll
    for (int j = 0; j < 4; j++) {
        const int n = n0 + wn * 64 + j * 16 + l16;
        const float bv_ = bp[n];
        #pragma unroll
        for (int i = 0; i < 4; i++) {
            const int mb = m0 + wm * 64 + i * 16 + quad * 4;
            #pragma unroll
            for (int r = 0; r < 4; r++) {
                const size_t idx = (size_t)(mb + r) * UU + n;
                out[idx] = acc[i][j][r] + bv_ + x[idx];
            }
        }
    }
}

// ---------------------------------------------------------------- launch
extern "C" void kernel_launch(void* const* d_in, const int* in_sizes, int n_in,
                              void* d_out, int out_size, void* d_ws, size_t ws_size,
                              hipStream_t stream)
{
    const float* x  = (const float*)d_in[0];
    const float* Wq = (const float*)d_in[1];
    const float* bq = (const float*)d_in[2];
    const float* Wk = (const float*)d_in[3];
    const float* bk = (const float*)d_in[4];
    const float* Wv = (const float*)d_in[5];
    const float* bv = (const float*)d_in[6];
    const float* Wp = (const float*)d_in[7];
    const float* bp = (const float*)d_in[8];
    float* out = (float*)d_out;

    char* ws = (char*)d_ws;
    unsigned short* Xb  = (unsigned short*)(ws);              // 16 MB  bf16 x
    unsigned short* WTb = (unsigned short*)(ws + 16777216);   // 4 x 512 KB contiguous
    unsigned short* WqT = WTb;
    unsigned short* WkT = WTb + 262144;
    unsigned short* WvT = WTb + 524288;
    unsigned short* WpT = WTb + 786432;
    unsigned short* Qm  = (unsigned short*)(ws + 18874368);   // 16 MB [b*N][U]
    unsigned short* K8m = (unsigned short*)(ws + 35651584);   // 16 MB [b][d>>3][key][d&7]
    unsigned short* V8m = (unsigned short*)(ws + 52428800);   // 16 MB [b][key>>3][d][key&7]
    unsigned short* Cx  = (unsigned short*)(ws + 69206016);   // 16 MB [b*N][U]

    hipLaunchKernelGGL(k_cvt_x, dim3(8192), dim3(256), 0, stream, x, Xb);
    hipLaunchKernelGGL(k_cvt_w4, dim3(1024, 4), dim3(256), 0, stream, Wq, Wk, Wv, Wp, WTb);
    hipLaunchKernelGGL(k_proj, dim3(128, 4, 3), dim3(256), 0, stream,
                       Xb, WqT, WkT, WvT, bq, bk, bv, Qm, K8m, V8m);
    hipLaunchKernelGGL(k_flash, dim3(64, 4), dim3(512), 0, stream, Qm, K8m, V8m, Cx);
    hipLaunchKernelGGL(k_out, dim3(128, 4), dim3(256), 0, stream, Cx, WpT, bp, x, out);
}